// Round 5
// baseline (1290.176 us; speedup 1.0000x reference)
//
#include <hip/hip_runtime.h>
#include <math.h>

#define EPS 1e-3f
#define H 256
#define QDIM 6
#define DQDIM 4
#define NTRI 10
#define EPB 8    // elements per block
#define PADH 260 // padded row length (floats)

typedef _Float16 half8 __attribute__((ext_vector_type(8)));
typedef float floatx4 __attribute__((ext_vector_type(4)));

#define WSZ (H * H)   // 65536 elements per weight matrix

__device__ __forceinline__ float softplusf(float x) {
    if (x > 20.f) return x;
    return log1pf(expf(x));
}

// split 8 contiguous floats into fp16 hi + fp16 residual lo
__device__ __forceinline__ void split8(const float* __restrict__ p, half8& hi, half8& lo) {
    #pragma unroll
    for (int i = 0; i < 8; i++) {
        float a = p[i];
        _Float16 h = (_Float16)a;
        hi[i] = h;
        lo[i] = (_Float16)(a - (float)h);
    }
}

#define MFMA(A, B, C) __builtin_amdgcn_mfma_f32_16x16x32_f16((A), (B), (C), 0, 0, 0)

// ---- prep: split weights to fp16 hi/lo in both layouts; transpose mW2 ----
__global__ __launch_bounds__(256) void prep_kernel(
    const float* __restrict__ mW1, const float* __restrict__ vW1,
    const float* __restrict__ mW2, void* __restrict__ ws)
{
    _Float16* W1t_hi = (_Float16*)ws;
    _Float16* W1t_lo = W1t_hi + WSZ;
    _Float16* W1m_hi = W1t_hi + 2 * WSZ;
    _Float16* W1m_lo = W1t_hi + 3 * WSZ;
    _Float16* V1t_hi = W1t_hi + 4 * WSZ;
    _Float16* V1t_lo = W1t_hi + 5 * WSZ;
    _Float16* V1m_hi = W1t_hi + 6 * WSZ;
    _Float16* V1m_lo = W1t_hi + 7 * WSZ;
    float*    W2t    = (float*)(W1t_hi + 8 * WSZ);

    const int k = blockIdx.x;
    const int j = threadIdx.x;
    {
        float a = mW1[k * H + j];
        _Float16 h = (_Float16)a;
        _Float16 l = (_Float16)(a - (float)h);
        W1m_hi[k * H + j] = h; W1m_lo[k * H + j] = l;
        W1t_hi[j * H + k] = h; W1t_lo[j * H + k] = l;
    }
    {
        float a = vW1[k * H + j];
        _Float16 h = (_Float16)a;
        _Float16 l = (_Float16)(a - (float)h);
        V1m_hi[k * H + j] = h; V1m_lo[k * H + j] = l;
        V1t_hi[j * H + k] = h; V1t_lo[j * H + k] = l;
    }
    if (k < NTRI) W2t[k * H + j] = mW2[j * NTRI + k];
}

__global__ __launch_bounds__(256) void lnn_kernel(
    const float* __restrict__ x,
    const float* __restrict__ mW0, const float* __restrict__ mb0,
    const float* __restrict__ mb1,
    const float* __restrict__ mW2, const float* __restrict__ mb2,
    const float* __restrict__ vW0, const float* __restrict__ vb0,
    const float* __restrict__ vb1,
    const float* __restrict__ vW2,
    const void* __restrict__ ws,
    float* __restrict__ out, int n)
{
    const _Float16* W1t_hi = (const _Float16*)ws;
    const _Float16* W1t_lo = W1t_hi + WSZ;
    const _Float16* W1m_hi = W1t_hi + 2 * WSZ;
    const _Float16* W1m_lo = W1t_hi + 3 * WSZ;
    const _Float16* V1t_hi = W1t_hi + 4 * WSZ;
    const _Float16* V1t_lo = W1t_hi + 5 * WSZ;
    const _Float16* V1m_hi = W1t_hi + 6 * WSZ;
    const _Float16* V1m_lo = W1t_hi + 7 * WSZ;
    const float*    W2t    = (const float*)(W1t_hi + 8 * WSZ);

    __shared__ float s_qd[EPB][12];
    __shared__ float s_h1[EPB][PADH];
    __shared__ float s_h2[EPB][PADH];
    __shared__ float s_eh2[EPB * 4][PADH];   // Eh2 seeds -> Eh1 -> gg1
    __shared__ float s_ent[EPB][NTRI];
    __shared__ float s_entbar[EPB][4][NTRI];
    __shared__ float s_L[EPB][4][4];
    __shared__ float s_J[EPB][4][6];
    __shared__ float s_dV[EPB][6];

    const int tid = threadIdx.x;
    const int e0 = blockIdx.x * EPB;
    const int lane = tid & 63;
    const int wid = tid >> 6;
    const int fr = lane & 15;
    const int fg = lane >> 4;

    // ---- load q, dq ----
    if (tid < EPB * 10) {
        int e = tid / 10, c = tid % 10;
        int ge = e0 + e;
        s_qd[e][c] = (ge < n) ? x[ge * 10 + c] : 0.f;
    }
    __syncthreads();

    // ---- mass MLP layer 0 ----
    {
        const int j = tid;
        float w[QDIM];
        #pragma unroll
        for (int i = 0; i < QDIM; i++) w[i] = mW0[i * H + j];
        const float b = mb0[j];
        #pragma unroll
        for (int e = 0; e < EPB; e++) {
            float z = b;
            #pragma unroll
            for (int i = 0; i < QDIM; i++) z += s_qd[e][i] * w[i];
            s_h1[e][j] = tanhf(z);
        }
    }
    __syncthreads();

    // ---- mass layer 1 via MFMA: h2 = tanh(h1 @ W1 + b1) ----
    {
        floatx4 acc[4];
        #pragma unroll
        for (int t = 0; t < 4; t++) acc[t] = (floatx4)(0.f);
        for (int kc = 0; kc < 8; kc++) {
            half8 ah, al;
            split8(&s_h1[fr & 7][kc * 32 + fg * 8], ah, al);
            #pragma unroll
            for (int t = 0; t < 4; t++) {
                const int j = (wid * 4 + t) * 16 + fr;
                const half8 bh = *(const half8*)&W1t_hi[j * H + kc * 32 + fg * 8];
                const half8 bl = *(const half8*)&W1t_lo[j * H + kc * 32 + fg * 8];
                acc[t] = MFMA(ah, bh, acc[t]);
                acc[t] = MFMA(ah, bl, acc[t]);
                acc[t] = MFMA(al, bh, acc[t]);
            }
        }
        if (fg < 2) {
            #pragma unroll
            for (int t = 0; t < 4; t++) {
                const int j = (wid * 4 + t) * 16 + fr;
                const float b = mb1[j];
                #pragma unroll
                for (int rr = 0; rr < 4; rr++) {
                    const int e = fg * 4 + rr;
                    s_h2[e][j] = tanhf(acc[t][rr] + b);
                }
            }
        }
    }
    __syncthreads();

    // ---- ent = h2 @ W2 + b2 (W2t contiguous) ----
    if (tid < EPB * NTRI) {
        int e = tid / NTRI, m = tid % NTRI;
        float acc = mb2[m];
        const float* wrow = &W2t[m * H];
        for (int j = 0; j < H; j += 4) {
            const float4 hv = *(const float4*)&s_h2[e][j];
            const float4 wv = *(const float4*)&wrow[j];
            acc += hv.x * wv.x + hv.y * wv.y + hv.z * wv.z + hv.w * wv.w;
        }
        s_ent[e][m] = acc;
    }
    __syncthreads();

    // ---- per-element: L, a = L^T dq, ent_bar seeds ----
    if (tid < EPB) {
        const int e = tid;
        const int ti[10] = {0,1,1,2,2,2,3,3,3,3};
        const int tj[10] = {0,0,1,0,1,2,0,1,2,3};
        float L[4][4];
        #pragma unroll
        for (int r = 0; r < 4; r++)
            #pragma unroll
            for (int c = 0; c < 4; c++) L[r][c] = 0.f;
        float sig[10];
        #pragma unroll
        for (int m = 0; m < 10; m++) {
            float v = s_ent[e][m];
            if (ti[m] == tj[m]) {
                sig[m] = 1.f / (1.f + expf(-v));
                L[ti[m]][tj[m]] = softplusf(v);
            } else {
                sig[m] = 1.f;
                L[ti[m]][tj[m]] = v;
            }
        }
        #pragma unroll
        for (int r = 0; r < 4; r++)
            #pragma unroll
            for (int c = 0; c < 4; c++) s_L[e][r][c] = L[r][c];
        float dq[4];
        #pragma unroll
        for (int r = 0; r < 4; r++) dq[r] = s_qd[e][6 + r];
        float a[4];
        #pragma unroll
        for (int c = 0; c < 4; c++) {
            float s = 0.f;
            #pragma unroll
            for (int r = 0; r < 4; r++) s += L[r][c] * dq[r];
            a[c] = s;
        }
        #pragma unroll
        for (int s = 0; s < 4; s++) {
            #pragma unroll
            for (int m = 0; m < 10; m++) {
                float v = ((ti[m] == s) ? a[tj[m]] : 0.f) + dq[ti[m]] * L[s][tj[m]];
                s_entbar[e][s][m] = v * sig[m];
            }
        }
    }
    __syncthreads();

    // ---- Eh2[e][s][j] = (1-h2^2) * (W2 @ ent_bar) ----
    {
        const int j = tid;
        float w2row[NTRI];
        #pragma unroll
        for (int m = 0; m < NTRI; m++) w2row[m] = mW2[j * NTRI + m];
        #pragma unroll
        for (int e = 0; e < EPB; e++) {
            const float h = s_h2[e][j];
            const float t2 = 1.f - h * h;
            #pragma unroll
            for (int s = 0; s < 4; s++) {
                float acc = 0.f;
                #pragma unroll
                for (int m = 0; m < NTRI; m++) acc += w2row[m] * s_entbar[e][s][m];
                s_eh2[e * 4 + s][j] = acc * t2;
            }
        }
    }
    __syncthreads();

    // ---- Eh1 via MFMA: Eh1[es][k] = t1[e][k] * sum_j W1[k,j]*Eh2[es][j] ----
    {
        floatx4 acc[4][2];
        #pragma unroll
        for (int t = 0; t < 4; t++)
            #pragma unroll
            for (int mt = 0; mt < 2; mt++) acc[t][mt] = (floatx4)(0.f);
        for (int kc = 0; kc < 8; kc++) {
            half8 ah[2], al[2];
            #pragma unroll
            for (int mt = 0; mt < 2; mt++)
                split8(&s_eh2[mt * 16 + fr][kc * 32 + fg * 8], ah[mt], al[mt]);
            #pragma unroll
            for (int t = 0; t < 4; t++) {
                const int outk = (wid * 4 + t) * 16 + fr;
                const half8 bh = *(const half8*)&W1m_hi[outk * H + kc * 32 + fg * 8];
                const half8 bl = *(const half8*)&W1m_lo[outk * H + kc * 32 + fg * 8];
                #pragma unroll
                for (int mt = 0; mt < 2; mt++) {
                    acc[t][mt] = MFMA(ah[mt], bh, acc[t][mt]);
                    acc[t][mt] = MFMA(ah[mt], bl, acc[t][mt]);
                    acc[t][mt] = MFMA(al[mt], bh, acc[t][mt]);
                }
            }
        }
        __syncthreads();   // all reads of Eh2 done before overwrite with Eh1
        #pragma unroll
        for (int t = 0; t < 4; t++) {
            const int outk = (wid * 4 + t) * 16 + fr;
            #pragma unroll
            for (int mt = 0; mt < 2; mt++) {
                const int e = mt * 4 + fg;
                const float h = s_h1[e][outk];
                const float t1 = 1.f - h * h;
                #pragma unroll
                for (int rr = 0; rr < 4; rr++)
                    s_eh2[mt * 16 + fg * 4 + rr][outk] = acc[t][mt][rr] * t1;
            }
        }
    }
    __syncthreads();

    // ---- J[e][s][i] = sum_k W0[i,k] * Eh1[es][k] ----
    if (tid < EPB * 4 * 6) {
        const int i = tid % 6;
        const int es = tid / 6;
        float acc = 0.f;
        for (int k = 0; k < H; k += 4) {
            const float4 w = *(const float4*)&mW0[i * H + k];
            const float4 v = *(const float4*)&s_eh2[es][k];
            acc += w.x * v.x + w.y * v.y + w.z * v.z + w.w * v.w;
        }
        s_J[es / 4][es % 4][i] = acc;
    }
    __syncthreads();

    // ---- V MLP layer 0 ----
    {
        const int j = tid;
        float w[QDIM];
        #pragma unroll
        for (int i = 0; i < QDIM; i++) w[i] = vW0[i * H + j];
        const float b = vb0[j];
        #pragma unroll
        for (int e = 0; e < EPB; e++) {
            float z = b;
            #pragma unroll
            for (int i = 0; i < QDIM; i++) z += s_qd[e][i] * w[i];
            s_h1[e][j] = tanhf(z);
        }
    }
    __syncthreads();

    // ---- V layer 1 via MFMA + seed: gg2 = (1-g2^2)*vW2[j] ----
    {
        floatx4 acc[4];
        #pragma unroll
        for (int t = 0; t < 4; t++) acc[t] = (floatx4)(0.f);
        for (int kc = 0; kc < 8; kc++) {
            half8 ah, al;
            split8(&s_h1[fr & 7][kc * 32 + fg * 8], ah, al);
            #pragma unroll
            for (int t = 0; t < 4; t++) {
                const int j = (wid * 4 + t) * 16 + fr;
                const half8 bh = *(const half8*)&V1t_hi[j * H + kc * 32 + fg * 8];
                const half8 bl = *(const half8*)&V1t_lo[j * H + kc * 32 + fg * 8];
                acc[t] = MFMA(ah, bh, acc[t]);
                acc[t] = MFMA(ah, bl, acc[t]);
                acc[t] = MFMA(al, bh, acc[t]);
            }
        }
        if (fg < 2) {
            #pragma unroll
            for (int t = 0; t < 4; t++) {
                const int j = (wid * 4 + t) * 16 + fr;
                const float b = vb1[j];
                const float w2 = vW2[j];
                #pragma unroll
                for (int rr = 0; rr < 4; rr++) {
                    const int e = fg * 4 + rr;
                    const float g2 = tanhf(acc[t][rr] + b);
                    s_h2[e][j] = (1.f - g2 * g2) * w2;
                }
            }
        }
    }
    __syncthreads();

    // ---- gg1 via MFMA: gg1[e][k] = t1g * sum_j vW1[k,j]*gg2[e][j] ----
    {
        floatx4 acc[4];
        #pragma unroll
        for (int t = 0; t < 4; t++) acc[t] = (floatx4)(0.f);
        for (int kc = 0; kc < 8; kc++) {
            half8 ah, al;
            split8(&s_h2[fr & 7][kc * 32 + fg * 8], ah, al);
            #pragma unroll
            for (int t = 0; t < 4; t++) {
                const int outk = (wid * 4 + t) * 16 + fr;
                const half8 bh = *(const half8*)&V1m_hi[outk * H + kc * 32 + fg * 8];
                const half8 bl = *(const half8*)&V1m_lo[outk * H + kc * 32 + fg * 8];
                acc[t] = MFMA(ah, bh, acc[t]);
                acc[t] = MFMA(ah, bl, acc[t]);
                acc[t] = MFMA(al, bh, acc[t]);
            }
        }
        __syncthreads();
        if (fg < 2) {
            #pragma unroll
            for (int t = 0; t < 4; t++) {
                const int outk = (wid * 4 + t) * 16 + fr;
                #pragma unroll
                for (int rr = 0; rr < 4; rr++) {
                    const int e = fg * 4 + rr;
                    const float g = s_h1[e][outk];
                    s_eh2[e][outk] = acc[t][rr] * (1.f - g * g);
                }
            }
        }
    }
    __syncthreads();

    // ---- dV[e][i] = sum_k vW0[i,k] * gg1[e][k] ----
    if (tid < EPB * 6) {
        const int e = tid / 6, i = tid % 6;
        float acc = 0.f;
        for (int k = 0; k < H; k += 4) {
            const float4 w = *(const float4*)&vW0[i * H + k];
            const float4 v = *(const float4*)&s_eh2[e][k];
            acc += w.x * v.x + w.y * v.y + w.z * v.z + w.w * v.w;
        }
        s_dV[e][i] = acc;
    }
    __syncthreads();

    // ---- finalize per element ----
    if (tid < EPB && (e0 + tid) < n) {
        const int e = tid;
        float q[6], dq[4];
        #pragma unroll
        for (int i = 0; i < 6; i++) q[i] = s_qd[e][i];
        #pragma unroll
        for (int r = 0; r < 4; r++) dq[r] = s_qd[e][6 + r];
        const float x1a = q[2], x1b = q[3], x2a = q[4], x2b = q[5];
        float J[4][6];
        #pragma unroll
        for (int r = 0; r < 4; r++)
            #pragma unroll
            for (int i = 0; i < 6; i++) J[r][i] = s_J[e][r][i];

        float G[4][4];
        #pragma unroll
        for (int r = 0; r < 4; r++) {
            G[r][0] = J[r][0];
            G[r][1] = J[r][1];
            G[r][2] = -x2a * J[r][2] + x1a * J[r][4];
            G[r][3] = -x2b * J[r][3] + x1b * J[r][5];
        }
        float gL[6];
        #pragma unroll
        for (int i = 0; i < 6; i++) {
            float s = 0.f;
            #pragma unroll
            for (int r = 0; r < 4; r++) s += dq[r] * J[r][i];
            gL[i] = 0.5f * s - s_dV[e][i];
        }
        float dLdq[4];
        dLdq[0] = gL[0];
        dLdq[1] = gL[1];
        dLdq[2] = -x2a * gL[2] + x1a * gL[4];
        dLdq[3] = -x2b * gL[3] + x1b * gL[5];
        float b[4];
        #pragma unroll
        for (int r = 0; r < 4; r++) {
            float s = 0.f;
            #pragma unroll
            for (int c = 0; c < 4; c++) s += G[r][c] * dq[c];
            b[r] = dLdq[r] - s;
        }
        float L[4][4];
        #pragma unroll
        for (int r = 0; r < 4; r++)
            #pragma unroll
            for (int c = 0; c < 4; c++) L[r][c] = s_L[e][r][c];
        float M[4][4];
        #pragma unroll
        for (int r = 0; r < 4; r++)
            #pragma unroll
            for (int c = 0; c <= r; c++) {
                float s = 0.f;
                #pragma unroll
                for (int k = 0; k < 4; k++) s += L[r][k] * L[c][k];
                M[r][c] = s;
            }
        #pragma unroll
        for (int r = 0; r < 4; r++) M[r][r] += EPS;
        float C00 = sqrtf(M[0][0]);
        float C10 = M[1][0] / C00, C20 = M[2][0] / C00, C30 = M[3][0] / C00;
        float C11 = sqrtf(M[1][1] - C10 * C10);
        float C21 = (M[2][1] - C20 * C10) / C11;
        float C31 = (M[3][1] - C30 * C10) / C11;
        float C22 = sqrtf(M[2][2] - C20 * C20 - C21 * C21);
        float C32 = (M[3][2] - C30 * C20 - C31 * C21) / C22;
        float C33 = sqrtf(M[3][3] - C30 * C30 - C31 * C31 - C32 * C32);
        float y0 = b[0] / C00;
        float y1 = (b[1] - C10 * y0) / C11;
        float y2 = (b[2] - C20 * y0 - C21 * y1) / C22;
        float y3 = (b[3] - C30 * y0 - C31 * y1 - C32 * y2) / C33;
        float d3 = y3 / C33;
        float d2 = (y2 - C32 * d3) / C22;
        float d1 = (y1 - C21 * d2 - C31 * d3) / C11;
        float d0 = (y0 - C10 * d1 - C20 * d2 - C30 * d3) / C00;

        float* o = &out[(e0 + e) * 10];
        o[0] = dq[0];
        o[1] = dq[1];
        o[2] = -x2a * dq[2];
        o[3] = -x2b * dq[3];
        o[4] = x1a * dq[2];
        o[5] = x1b * dq[3];
        o[6] = d0; o[7] = d1; o[8] = d2; o[9] = d3;
    }
}

extern "C" void kernel_launch(void* const* d_in, const int* in_sizes, int n_in,
                              void* d_out, int out_size, void* d_ws, size_t ws_size,
                              hipStream_t stream) {
    const float* x   = (const float*)d_in[0];
    const float* mW0 = (const float*)d_in[1];
    const float* mb0 = (const float*)d_in[2];
    const float* mW1 = (const float*)d_in[3];
    const float* mb1 = (const float*)d_in[4];
    const float* mW2 = (const float*)d_in[5];
    const float* mb2 = (const float*)d_in[6];
    const float* vW0 = (const float*)d_in[7];
    const float* vb0 = (const float*)d_in[8];
    const float* vW1 = (const float*)d_in[9];
    const float* vb1 = (const float*)d_in[10];
    const float* vW2 = (const float*)d_in[11];
    float* out = (float*)d_out;
    const int n = in_sizes[0] / 10;

    prep_kernel<<<H, H, 0, stream>>>(mW1, vW1, mW2, d_ws);

    const int blocks = (n + EPB - 1) / EPB;
    lnn_kernel<<<blocks, 256, 0, stream>>>(x, mW0, mb0, mb1, mW2, mb2,
                                           vW0, vb0, vb1, vW2,
                                           d_ws, out, n);
}

// Round 6
// 1176.846 us; speedup vs baseline: 1.0963x; 1.0963x over previous
//
#include <hip/hip_runtime.h>
#include <math.h>

#define EPS 1e-3f
#define H 256
#define QDIM 6
#define NTRI 10
#define EPB 8     // elements per block
#define PADH 258  // padded row length (floats): stride*4B spreads banks, 8B-aligned

typedef _Float16 half8 __attribute__((ext_vector_type(8)));
typedef float floatx4 __attribute__((ext_vector_type(4)));

#define WSZ (H * H)

__device__ __forceinline__ float softplusf(float x) {
    if (x > 20.f) return x;
    return log1pf(expf(x));
}

// split 8 contiguous floats (LDS) into fp16 hi + residual lo
__device__ __forceinline__ void split8(const float* __restrict__ p, half8& hi, half8& lo) {
    #pragma unroll
    for (int i = 0; i < 8; i++) {
        float a = p[i];
        _Float16 h = (_Float16)a;
        hi[i] = h;
        lo[i] = (_Float16)(a - (float)h);
    }
}

// split two float4 registers into fp16 hi + residual lo
__device__ __forceinline__ void splitf8(const float4 a, const float4 b, half8& hi, half8& lo) {
    const float v[8] = {a.x, a.y, a.z, a.w, b.x, b.y, b.z, b.w};
    #pragma unroll
    for (int i = 0; i < 8; i++) {
        _Float16 h = (_Float16)v[i];
        hi[i] = h;
        lo[i] = (_Float16)(v[i] - (float)h);
    }
}

#define MFMA(A, B, C) __builtin_amdgcn_mfma_f32_16x16x32_f16((A), (B), (C), 0, 0, 0)

// ---- prep: fp32 transposes for contiguous forward B loads ----
__global__ __launch_bounds__(256) void prep_kernel(
    const float* __restrict__ mW1, const float* __restrict__ vW1,
    const float* __restrict__ mW2, float* __restrict__ ws)
{
    float* W1t = ws;               // [j*H + k] = mW1[k*H + j]
    float* V1t = ws + WSZ;
    float* W2t = ws + 2 * WSZ;     // [m*H + j] = mW2[j*NTRI + m]
    const int k = blockIdx.x;
    const int j = threadIdx.x;
    W1t[j * H + k] = mW1[k * H + j];
    V1t[j * H + k] = vW1[k * H + j];
    if (k < NTRI) W2t[k * H + j] = mW2[j * NTRI + k];
}

__global__ __launch_bounds__(256, 3) void lnn_kernel(
    const float* __restrict__ x,
    const float* __restrict__ mW0, const float* __restrict__ mb0,
    const float* __restrict__ mW1, const float* __restrict__ mb1,
    const float* __restrict__ mW2, const float* __restrict__ mb2,
    const float* __restrict__ vW0, const float* __restrict__ vb0,
    const float* __restrict__ vW1, const float* __restrict__ vb1,
    const float* __restrict__ vW2,
    const float* __restrict__ ws,
    float* __restrict__ out, int n)
{
    const float* W1t = ws;
    const float* V1t = ws + WSZ;
    const float* W2t = ws + 2 * WSZ;

    __shared__ float s_qd[EPB][10];
    __shared__ float s_h1[EPB][PADH];
    __shared__ float s_h2[EPB][PADH];
    __shared__ float s_eh2[EPB * 4][PADH];   // E seeds (A-operand of Eh1)
    __shared__ float s_U[960];               // {ent(80), entbar(320)} then {Jp(768), dVp(192)}
    __shared__ float s_L[EPB][16];

    float (*s_ent)[NTRI]       = (float (*)[NTRI])s_U;
    float (*s_entbar)[4][NTRI] = (float (*)[4][NTRI])(s_U + 80);
    float (*s_Jp)[EPB][4][6]   = (float (*)[EPB][4][6])s_U;          // [wid][e][s][i]
    float (*s_dVp)[EPB][6]     = (float (*)[EPB][6])(s_U + 768);     // [wid][e][i]

    const int tid = threadIdx.x;
    const int e0 = blockIdx.x * EPB;
    const int lane = tid & 63;
    const int wid = tid >> 6;
    const int fr = lane & 15;
    const int fg = lane >> 4;
    const int kb = fg * 8;

    // ---- load q, dq ----
    if (tid < EPB * 10) {
        int e = tid / 10, c = tid % 10;
        int ge = e0 + e;
        s_qd[e][c] = (ge < n) ? x[ge * 10 + c] : 0.f;
    }
    __syncthreads();

    // ---- mass MLP layer 0 ----
    {
        const int j = tid;
        float w[QDIM];
        #pragma unroll
        for (int i = 0; i < QDIM; i++) w[i] = mW0[i * H + j];
        const float b = mb0[j];
        #pragma unroll
        for (int e = 0; e < EPB; e++) {
            float z = b;
            #pragma unroll
            for (int i = 0; i < QDIM; i++) z += s_qd[e][i] * w[i];
            s_h1[e][j] = tanhf(z);
        }
    }
    __syncthreads();

    // ---- mass layer 1 via MFMA (B: W1t fp32 contiguous, 2-deep prefetch) ----
    {
        floatx4 acc[4];
        #pragma unroll
        for (int t = 0; t < 4; t++) acc[t] = (floatx4)(0.f);
        float4 bA[4][2], bB[4][2];
        auto PREF = [&](float4 (&buf)[4][2], int kc) {
            #pragma unroll
            for (int t = 0; t < 4; t++) {
                const float* p = &W1t[((wid * 4 + t) * 16 + fr) * H + kc * 32 + kb];
                buf[t][0] = *(const float4*)p;
                buf[t][1] = *(const float4*)(p + 4);
            }
        };
        auto STEP = [&](float4 (&buf)[4][2], int kc) {
            half8 ah, al;
            split8(&s_h1[fr & 7][kc * 32 + kb], ah, al);
            #pragma unroll
            for (int t = 0; t < 4; t++) {
                half8 bh, bl;
                splitf8(buf[t][0], buf[t][1], bh, bl);
                acc[t] = MFMA(ah, bh, acc[t]);
                acc[t] = MFMA(ah, bl, acc[t]);
                acc[t] = MFMA(al, bh, acc[t]);
            }
        };
        PREF(bA, 0);
        PREF(bB, 1); STEP(bA, 0);
        PREF(bA, 2); STEP(bB, 1);
        PREF(bB, 3); STEP(bA, 2);
        PREF(bA, 4); STEP(bB, 3);
        PREF(bB, 5); STEP(bA, 4);
        PREF(bA, 6); STEP(bB, 5);
        PREF(bB, 7); STEP(bA, 6);
        STEP(bB, 7);
        if (fg < 2) {
            #pragma unroll
            for (int t = 0; t < 4; t++) {
                const int j = (wid * 4 + t) * 16 + fr;
                const float b = mb1[j];
                #pragma unroll
                for (int rr = 0; rr < 4; rr++)
                    s_h2[fg * 4 + rr][j] = tanhf(acc[t][rr] + b);
            }
        }
    }
    __syncthreads();

    // ---- ent = h2 @ W2 + b2 (float2: rows 8B-aligned) ----
    if (tid < EPB * NTRI) {
        int e = tid / NTRI, m = tid % NTRI;
        float acc = mb2[m];
        const float* wrow = &W2t[m * H];
        for (int j = 0; j < H; j += 4) {
            const float2 h0 = *(const float2*)&s_h2[e][j];
            const float2 h1 = *(const float2*)&s_h2[e][j + 2];
            const float4 wv = *(const float4*)&wrow[j];
            acc += h0.x * wv.x + h0.y * wv.y + h1.x * wv.z + h1.y * wv.w;
        }
        s_ent[e][m] = acc;
    }
    __syncthreads();

    // ---- per-element: L, a = L^T dq, ent_bar seeds ----
    if (tid < EPB) {
        const int e = tid;
        const int ti[10] = {0,1,1,2,2,2,3,3,3,3};
        const int tj[10] = {0,0,1,0,1,2,0,1,2,3};
        float L[4][4];
        #pragma unroll
        for (int r = 0; r < 4; r++)
            #pragma unroll
            for (int c = 0; c < 4; c++) L[r][c] = 0.f;
        float sig[10];
        #pragma unroll
        for (int m = 0; m < 10; m++) {
            float v = s_ent[e][m];
            if (ti[m] == tj[m]) {
                sig[m] = 1.f / (1.f + expf(-v));
                L[ti[m]][tj[m]] = softplusf(v);
            } else {
                sig[m] = 1.f;
                L[ti[m]][tj[m]] = v;
            }
        }
        #pragma unroll
        for (int r = 0; r < 4; r++)
            #pragma unroll
            for (int c = 0; c < 4; c++) s_L[e][r * 4 + c] = L[r][c];
        float dq[4];
        #pragma unroll
        for (int r = 0; r < 4; r++) dq[r] = s_qd[e][6 + r];
        float a[4];
        #pragma unroll
        for (int c = 0; c < 4; c++) {
            float s = 0.f;
            #pragma unroll
            for (int r = 0; r < 4; r++) s += L[r][c] * dq[r];
            a[c] = s;
        }
        #pragma unroll
        for (int s = 0; s < 4; s++) {
            #pragma unroll
            for (int m = 0; m < 10; m++) {
                float v = ((ti[m] == s) ? a[tj[m]] : 0.f) + dq[ti[m]] * L[s][tj[m]];
                s_entbar[e][s][m] = v * sig[m];
            }
        }
    }
    __syncthreads();

    // ---- Eh2[e][s][j] = (1-h2^2) * (W2 @ ent_bar) ----
    {
        const int j = tid;
        float w2row[NTRI];
        #pragma unroll
        for (int m = 0; m < NTRI; m++) w2row[m] = mW2[j * NTRI + m];
        #pragma unroll
        for (int e = 0; e < EPB; e++) {
            const float h = s_h2[e][j];
            const float t2 = 1.f - h * h;
            #pragma unroll
            for (int s = 0; s < 4; s++) {
                float acc = 0.f;
                #pragma unroll
                for (int m = 0; m < NTRI; m++) acc += w2row[m] * s_entbar[e][s][m];
                s_eh2[e * 4 + s][j] = acc * t2;
            }
        }
    }
    __syncthreads();

    // ---- Eh1 via MFMA (B: mW1 rows contiguous, prefetched) + fused J reduce ----
    {
        floatx4 acc[4][2];
        #pragma unroll
        for (int t = 0; t < 4; t++)
            #pragma unroll
            for (int mt = 0; mt < 2; mt++) acc[t][mt] = (floatx4)(0.f);
        float4 bA[4][2], bB[4][2];
        auto PREF = [&](float4 (&buf)[4][2], int kc) {
            #pragma unroll
            for (int t = 0; t < 4; t++) {
                const float* p = &mW1[((wid * 4 + t) * 16 + fr) * H + kc * 32 + kb];
                buf[t][0] = *(const float4*)p;
                buf[t][1] = *(const float4*)(p + 4);
            }
        };
        auto STEP = [&](float4 (&buf)[4][2], int kc) {
            half8 ah[2], al[2];
            #pragma unroll
            for (int mt = 0; mt < 2; mt++)
                split8(&s_eh2[mt * 16 + fr][kc * 32 + kb], ah[mt], al[mt]);
            #pragma unroll
            for (int t = 0; t < 4; t++) {
                half8 bh, bl;
                splitf8(buf[t][0], buf[t][1], bh, bl);
                #pragma unroll
                for (int mt = 0; mt < 2; mt++) {
                    acc[t][mt] = MFMA(ah[mt], bh, acc[t][mt]);
                    acc[t][mt] = MFMA(ah[mt], bl, acc[t][mt]);
                    acc[t][mt] = MFMA(al[mt], bh, acc[t][mt]);
                }
            }
        };
        PREF(bA, 0);
        PREF(bB, 1); STEP(bA, 0);
        PREF(bA, 2); STEP(bB, 1);
        PREF(bB, 3); STEP(bA, 2);
        PREF(bA, 4); STEP(bB, 3);
        PREF(bB, 5); STEP(bA, 4);
        PREF(bA, 6); STEP(bB, 5);
        PREF(bB, 7); STEP(bA, 6);
        STEP(bB, 7);

        // fused J: J[e][s][i] = sum_k W0[i,k] * t1[e][k] * acc
        float w0v[4][6];
        #pragma unroll
        for (int t = 0; t < 4; t++) {
            const int outk = (wid * 4 + t) * 16 + fr;
            #pragma unroll
            for (int i = 0; i < 6; i++) w0v[t][i] = mW0[i * H + outk];
        }
        #pragma unroll
        for (int mt = 0; mt < 2; mt++) {
            const int e = mt * 4 + fg;
            float part[4][6];
            #pragma unroll
            for (int rr = 0; rr < 4; rr++)
                #pragma unroll
                for (int i = 0; i < 6; i++) part[rr][i] = 0.f;
            #pragma unroll
            for (int t = 0; t < 4; t++) {
                const int outk = (wid * 4 + t) * 16 + fr;
                const float h = s_h1[e][outk];
                const float t1 = 1.f - h * h;
                #pragma unroll
                for (int rr = 0; rr < 4; rr++) {
                    const float v = acc[t][mt][rr] * t1;
                    #pragma unroll
                    for (int i = 0; i < 6; i++) part[rr][i] = fmaf(v, w0v[t][i], part[rr][i]);
                }
            }
            #pragma unroll
            for (int m = 1; m < 16; m <<= 1)
                #pragma unroll
                for (int rr = 0; rr < 4; rr++)
                    #pragma unroll
                    for (int i = 0; i < 6; i++)
                        part[rr][i] += __shfl_xor(part[rr][i], m);
            if (fr == 0) {
                #pragma unroll
                for (int rr = 0; rr < 4; rr++)
                    #pragma unroll
                    for (int i = 0; i < 6; i++)
                        s_Jp[wid][e][rr][i] = part[rr][i];
            }
        }
    }
    __syncthreads();

    // ---- V MLP layer 0 (overwrite s_h1) ----
    {
        const int j = tid;
        float w[QDIM];
        #pragma unroll
        for (int i = 0; i < QDIM; i++) w[i] = vW0[i * H + j];
        const float b = vb0[j];
        #pragma unroll
        for (int e = 0; e < EPB; e++) {
            float z = b;
            #pragma unroll
            for (int i = 0; i < QDIM; i++) z += s_qd[e][i] * w[i];
            s_h1[e][j] = tanhf(z);
        }
    }
    __syncthreads();

    // ---- V layer 1 via MFMA (B: V1t contiguous, prefetched): gg2 -> s_h2 ----
    {
        floatx4 acc[4];
        #pragma unroll
        for (int t = 0; t < 4; t++) acc[t] = (floatx4)(0.f);
        float4 bA[4][2], bB[4][2];
        auto PREF = [&](float4 (&buf)[4][2], int kc) {
            #pragma unroll
            for (int t = 0; t < 4; t++) {
                const float* p = &V1t[((wid * 4 + t) * 16 + fr) * H + kc * 32 + kb];
                buf[t][0] = *(const float4*)p;
                buf[t][1] = *(const float4*)(p + 4);
            }
        };
        auto STEP = [&](float4 (&buf)[4][2], int kc) {
            half8 ah, al;
            split8(&s_h1[fr & 7][kc * 32 + kb], ah, al);
            #pragma unroll
            for (int t = 0; t < 4; t++) {
                half8 bh, bl;
                splitf8(buf[t][0], buf[t][1], bh, bl);
                acc[t] = MFMA(ah, bh, acc[t]);
                acc[t] = MFMA(ah, bl, acc[t]);
                acc[t] = MFMA(al, bh, acc[t]);
            }
        };
        PREF(bA, 0);
        PREF(bB, 1); STEP(bA, 0);
        PREF(bA, 2); STEP(bB, 1);
        PREF(bB, 3); STEP(bA, 2);
        PREF(bA, 4); STEP(bB, 3);
        PREF(bB, 5); STEP(bA, 4);
        PREF(bA, 6); STEP(bB, 5);
        PREF(bB, 7); STEP(bA, 6);
        STEP(bB, 7);
        if (fg < 2) {
            #pragma unroll
            for (int t = 0; t < 4; t++) {
                const int j = (wid * 4 + t) * 16 + fr;
                const float b = vb1[j];
                const float w2 = vW2[j];
                #pragma unroll
                for (int rr = 0; rr < 4; rr++) {
                    const float g2 = tanhf(acc[t][rr] + b);
                    s_h2[fg * 4 + rr][j] = (1.f - g2 * g2) * w2;
                }
            }
        }
    }
    __syncthreads();

    // ---- gg1 via MFMA (B: vW1 rows contiguous, prefetched) + fused dV reduce ----
    {
        floatx4 acc[4];
        #pragma unroll
        for (int t = 0; t < 4; t++) acc[t] = (floatx4)(0.f);
        float4 bA[4][2], bB[4][2];
        auto PREF = [&](float4 (&buf)[4][2], int kc) {
            #pragma unroll
            for (int t = 0; t < 4; t++) {
                const float* p = &vW1[((wid * 4 + t) * 16 + fr) * H + kc * 32 + kb];
                buf[t][0] = *(const float4*)p;
                buf[t][1] = *(const float4*)(p + 4);
            }
        };
        auto STEP = [&](float4 (&buf)[4][2], int kc) {
            half8 ah, al;
            split8(&s_h2[fr & 7][kc * 32 + kb], ah, al);
            #pragma unroll
            for (int t = 0; t < 4; t++) {
                half8 bh, bl;
                splitf8(buf[t][0], buf[t][1], bh, bl);
                acc[t] = MFMA(ah, bh, acc[t]);
                acc[t] = MFMA(ah, bl, acc[t]);
                acc[t] = MFMA(al, bh, acc[t]);
            }
        };
        PREF(bA, 0);
        PREF(bB, 1); STEP(bA, 0);
        PREF(bA, 2); STEP(bB, 1);
        PREF(bB, 3); STEP(bA, 2);
        PREF(bA, 4); STEP(bB, 3);
        PREF(bB, 5); STEP(bA, 4);
        PREF(bA, 6); STEP(bB, 5);
        PREF(bB, 7); STEP(bA, 6);
        STEP(bB, 7);

        // fused dV: dV[e][i] = sum_k vW0[i,k] * (1-g1^2)[e][k] * acc
        float w0v[4][6];
        #pragma unroll
        for (int t = 0; t < 4; t++) {
            const int outk = (wid * 4 + t) * 16 + fr;
            #pragma unroll
            for (int i = 0; i < 6; i++) w0v[t][i] = vW0[i * H + outk];
        }
        float part[4][6];
        #pragma unroll
        for (int rr = 0; rr < 4; rr++)
            #pragma unroll
            for (int i = 0; i < 6; i++) part[rr][i] = 0.f;
        #pragma unroll
        for (int t = 0; t < 4; t++) {
            const int outk = (wid * 4 + t) * 16 + fr;
            #pragma unroll
            for (int rr = 0; rr < 4; rr++) {
                const float h = s_h1[(fg * 4 + rr) & 7][outk];
                const float t1 = 1.f - h * h;
                const float v = acc[t][rr] * t1;
                #pragma unroll
                for (int i = 0; i < 6; i++) part[rr][i] = fmaf(v, w0v[t][i], part[rr][i]);
            }
        }
        #pragma unroll
        for (int m = 1; m < 16; m <<= 1)
            #pragma unroll
            for (int rr = 0; rr < 4; rr++)
                #pragma unroll
                for (int i = 0; i < 6; i++)
                    part[rr][i] += __shfl_xor(part[rr][i], m);
        if (fr == 0 && fg < 2) {
            #pragma unroll
            for (int rr = 0; rr < 4; rr++)
                #pragma unroll
                for (int i = 0; i < 6; i++)
                    s_dVp[wid][fg * 4 + rr][i] = part[rr][i];
        }
    }
    __syncthreads();

    // ---- finalize per element ----
    if (tid < EPB && (e0 + tid) < n) {
        const int e = tid;
        float q[6], dq[4];
        #pragma unroll
        for (int i = 0; i < 6; i++) q[i] = s_qd[e][i];
        #pragma unroll
        for (int r = 0; r < 4; r++) dq[r] = s_qd[e][6 + r];
        const float x1a = q[2], x1b = q[3], x2a = q[4], x2b = q[5];
        float J[4][6];
        #pragma unroll
        for (int r = 0; r < 4; r++)
            #pragma unroll
            for (int i = 0; i < 6; i++)
                J[r][i] = s_Jp[0][e][r][i] + s_Jp[1][e][r][i] + s_Jp[2][e][r][i] + s_Jp[3][e][r][i];
        float dV[6];
        #pragma unroll
        for (int i = 0; i < 6; i++)
            dV[i] = s_dVp[0][e][i] + s_dVp[1][e][i] + s_dVp[2][e][i] + s_dVp[3][e][i];

        float G[4][4];
        #pragma unroll
        for (int r = 0; r < 4; r++) {
            G[r][0] = J[r][0];
            G[r][1] = J[r][1];
            G[r][2] = -x2a * J[r][2] + x1a * J[r][4];
            G[r][3] = -x2b * J[r][3] + x1b * J[r][5];
        }
        float gL[6];
        #pragma unroll
        for (int i = 0; i < 6; i++) {
            float s = 0.f;
            #pragma unroll
            for (int r = 0; r < 4; r++) s += dq[r] * J[r][i];
            gL[i] = 0.5f * s - dV[i];
        }
        float dLdq[4];
        dLdq[0] = gL[0];
        dLdq[1] = gL[1];
        dLdq[2] = -x2a * gL[2] + x1a * gL[4];
        dLdq[3] = -x2b * gL[3] + x1b * gL[5];
        float b[4];
        #pragma unroll
        for (int r = 0; r < 4; r++) {
            float s = 0.f;
            #pragma unroll
            for (int c = 0; c < 4; c++) s += G[r][c] * dq[c];
            b[r] = dLdq[r] - s;
        }
        float L[4][4];
        #pragma unroll
        for (int r = 0; r < 4; r++)
            #pragma unroll
            for (int c = 0; c < 4; c++) L[r][c] = s_L[e][r * 4 + c];
        float M[4][4];
        #pragma unroll
        for (int r = 0; r < 4; r++)
            #pragma unroll
            for (int c = 0; c <= r; c++) {
                float s = 0.f;
                #pragma unroll
                for (int k = 0; k < 4; k++) s += L[r][k] * L[c][k];
                M[r][c] = s;
            }
        #pragma unroll
        for (int r = 0; r < 4; r++) M[r][r] += EPS;
        float C00 = sqrtf(M[0][0]);
        float C10 = M[1][0] / C00, C20 = M[2][0] / C00, C30 = M[3][0] / C00;
        float C11 = sqrtf(M[1][1] - C10 * C10);
        float C21 = (M[2][1] - C20 * C10) / C11;
        float C31 = (M[3][1] - C30 * C10) / C11;
        float C22 = sqrtf(M[2][2] - C20 * C20 - C21 * C21);
        float C32 = (M[3][2] - C30 * C20 - C31 * C21) / C22;
        float C33 = sqrtf(M[3][3] - C30 * C30 - C31 * C31 - C32 * C32);
        float y0 = b[0] / C00;
        float y1 = (b[1] - C10 * y0) / C11;
        float y2 = (b[2] - C20 * y0 - C21 * y1) / C22;
        float y3 = (b[3] - C30 * y0 - C31 * y1 - C32 * y2) / C33;
        float d3 = y3 / C33;
        float d2 = (y2 - C32 * d3) / C22;
        float d1 = (y1 - C21 * d2 - C31 * d3) / C11;
        float d0 = (y0 - C10 * d1 - C20 * d2 - C30 * d3) / C00;

        float* o = &out[(e0 + e) * 10];
        o[0] = dq[0];
        o[1] = dq[1];
        o[2] = -x2a * dq[2];
        o[3] = -x2b * dq[3];
        o[4] = x1a * dq[2];
        o[5] = x1b * dq[3];
        o[6] = d0; o[7] = d1; o[8] = d2; o[9] = d3;
    }
}

extern "C" void kernel_launch(void* const* d_in, const int* in_sizes, int n_in,
                              void* d_out, int out_size, void* d_ws, size_t ws_size,
                              hipStream_t stream) {
    const float* x   = (const float*)d_in[0];
    const float* mW0 = (const float*)d_in[1];
    const float* mb0 = (const float*)d_in[2];
    const float* mW1 = (const float*)d_in[3];
    const float* mb1 = (const float*)d_in[4];
    const float* mW2 = (const float*)d_in[5];
    const float* mb2 = (const float*)d_in[6];
    const float* vW0 = (const float*)d_in[7];
    const float* vb0 = (const float*)d_in[8];
    const float* vW1 = (const float*)d_in[9];
    const float* vb1 = (const float*)d_in[10];
    const float* vW2 = (const float*)d_in[11];
    float* out = (float*)d_out;
    const int n = in_sizes[0] / 10;

    prep_kernel<<<H, H, 0, stream>>>(mW1, vW1, mW2, (float*)d_ws);

    const int blocks = (n + EPB - 1) / EPB;
    lnn_kernel<<<blocks, 256, 0, stream>>>(x, mW0, mb0, mW1, mb1, mW2, mb2,
                                           vW0, vb0, vW1, vb1, vW2,
                                           (const float*)d_ws, out, n);
}

// Round 7
// 1099.486 us; speedup vs baseline: 1.1734x; 1.0704x over previous
//
#include <hip/hip_runtime.h>
#include <math.h>

#define EPS 1e-3f
#define H 256
#define QDIM 6
#define NTRI 10
#define EPB 8
#define PADH 258   // fp32 activation row pad (dwords)

typedef _Float16 half8 __attribute__((ext_vector_type(8)));
typedef float floatx4 __attribute__((ext_vector_type(4)));

#define WSZ (H * H)

__device__ __forceinline__ float softplusf(float x) {
    if (x > 20.f) return x;
    return log1pf(expf(x));
}

// split 8 contiguous floats (LDS) into fp16 hi + residual lo
__device__ __forceinline__ void split8(const float* __restrict__ p, half8& hi, half8& lo) {
    #pragma unroll
    for (int i = 0; i < 8; i++) {
        float a = p[i];
        _Float16 h = (_Float16)a;
        hi[i] = h;
        lo[i] = (_Float16)(a - (float)h);
    }
}

#define MFMA(A, B, C) __builtin_amdgcn_mfma_f32_16x16x32_f16((A), (B), (C), 0, 0, 0)

// ---- prep: pre-split weights to fp16 hi/lo in both layouts; transpose mW2 ----
// ws halfs layout: [0]W1t_hi [1]W1t_lo [2]W1m_hi [3]W1m_lo
//                  [4]V1t_hi [5]V1t_lo [6]V1m_hi [7]V1m_lo ; then W2t fp32
__global__ __launch_bounds__(256) void prep_kernel(
    const float* __restrict__ mW1, const float* __restrict__ vW1,
    const float* __restrict__ mW2, void* __restrict__ ws)
{
    _Float16* h = (_Float16*)ws;
    float* W2t = (float*)(h + 8 * WSZ);
    const int k = blockIdx.x;   // row of W1
    const int j = threadIdx.x;  // col of W1
    {
        float a = mW1[k * H + j];
        _Float16 hi = (_Float16)a;
        _Float16 lo = (_Float16)(a - (float)hi);
        h[0 * WSZ + j * H + k] = hi;   // W1t_hi
        h[1 * WSZ + j * H + k] = lo;   // W1t_lo
        h[2 * WSZ + k * H + j] = hi;   // W1m_hi
        h[3 * WSZ + k * H + j] = lo;   // W1m_lo
    }
    {
        float a = vW1[k * H + j];
        _Float16 hi = (_Float16)a;
        _Float16 lo = (_Float16)(a - (float)hi);
        h[4 * WSZ + j * H + k] = hi;   // V1t_hi
        h[5 * WSZ + j * H + k] = lo;   // V1t_lo
        h[6 * WSZ + k * H + j] = hi;   // V1m_hi
        h[7 * WSZ + k * H + j] = lo;   // V1m_lo
    }
    if (k < NTRI) W2t[k * H + j] = mW2[j * NTRI + k];
}

__global__ __launch_bounds__(256, 3) void lnn_kernel(
    const float* __restrict__ x,
    const float* __restrict__ mW0, const float* __restrict__ mb0,
    const float* __restrict__ mb1,
    const float* __restrict__ mW2, const float* __restrict__ mb2,
    const float* __restrict__ vW0, const float* __restrict__ vb0,
    const float* __restrict__ vb1,
    const float* __restrict__ vW2,
    const void* __restrict__ ws,
    float* __restrict__ out, int n)
{
    const _Float16* wsh = (const _Float16*)ws;
    const _Float16* W1t_hi = wsh + 0 * WSZ;
    const _Float16* W1t_lo = wsh + 1 * WSZ;
    const _Float16* W1m_hi = wsh + 2 * WSZ;
    const _Float16* W1m_lo = wsh + 3 * WSZ;
    const _Float16* V1t_hi = wsh + 4 * WSZ;
    const _Float16* V1t_lo = wsh + 5 * WSZ;
    const _Float16* V1m_hi = wsh + 6 * WSZ;
    const _Float16* V1m_lo = wsh + 7 * WSZ;
    const float*    W2t    = (const float*)(wsh + 8 * WSZ);

    __shared__ float s_qd[EPB][10];
    __shared__ float s_h1[EPB][PADH];
    __shared__ float s_h2[EPB][PADH];
    __shared__ _Float16 __align__(16) s_sH[32 * 256];  // seed hi, XOR-swizzled
    __shared__ _Float16 __align__(16) s_sL[32 * 256];  // seed lo
    __shared__ float s_U[960];   // {ent(80), entbar(320)} then {Jp(768), dVp(192)}

    float (*s_ent)[NTRI]       = (float (*)[NTRI])s_U;
    float (*s_entbar)[4][NTRI] = (float (*)[4][NTRI])(s_U + 80);
    float (*s_Jp)[EPB][4][6]   = (float (*)[EPB][4][6])s_U;       // [wid][e][s][i]
    float (*s_dVp)[EPB][6]     = (float (*)[EPB][6])(s_U + 768);  // [wid][e][i]

    const int tid = threadIdx.x;
    const int e0 = blockIdx.x * EPB;
    const int lane = tid & 63;
    const int wid = tid >> 6;
    const int fr = lane & 15;
    const int fg = lane >> 4;
    const int kb = fg * 8;

    float Lreg[4][4];   // threads 0..7: per-element L, producer==consumer

    // ---- load q, dq ----
    if (tid < EPB * 10) {
        int e = tid / 10, c = tid % 10;
        int ge = e0 + e;
        s_qd[e][c] = (ge < n) ? x[ge * 10 + c] : 0.f;
    }
    __syncthreads();

    // ---- mass MLP layer 0 ----
    {
        const int j = tid;
        float w[QDIM];
        #pragma unroll
        for (int i = 0; i < QDIM; i++) w[i] = mW0[i * H + j];
        const float b = mb0[j];
        #pragma unroll
        for (int e = 0; e < EPB; e++) {
            float z = b;
            #pragma unroll
            for (int i = 0; i < QDIM; i++) z += s_qd[e][i] * w[i];
            s_h1[e][j] = tanhf(z);
        }
    }
    __syncthreads();

    // ---- mass layer 1 via MFMA (B pre-split fp16, 2-deep prefetch) ----
    {
        floatx4 acc[4];
        #pragma unroll
        for (int t = 0; t < 4; t++) acc[t] = (floatx4)(0.f);
        half8 bhA[4], blA[4], bhB[4], blB[4];
        auto PREF = [&](half8 (&bh)[4], half8 (&bl)[4], int kc) {
            #pragma unroll
            for (int t = 0; t < 4; t++) {
                const int off = ((wid * 4 + t) * 16 + fr) * H + kc * 32 + kb;
                bh[t] = *(const half8*)&W1t_hi[off];
                bl[t] = *(const half8*)&W1t_lo[off];
            }
        };
        auto STEP = [&](half8 (&bh)[4], half8 (&bl)[4], int kc) {
            half8 ah, al;
            split8(&s_h1[fr & 7][kc * 32 + kb], ah, al);
            #pragma unroll
            for (int t = 0; t < 4; t++) {
                acc[t] = MFMA(ah, bh[t], acc[t]);
                acc[t] = MFMA(ah, bl[t], acc[t]);
                acc[t] = MFMA(al, bh[t], acc[t]);
            }
        };
        PREF(bhA, blA, 0);
        PREF(bhB, blB, 1); STEP(bhA, blA, 0);
        PREF(bhA, blA, 2); STEP(bhB, blB, 1);
        PREF(bhB, blB, 3); STEP(bhA, blA, 2);
        PREF(bhA, blA, 4); STEP(bhB, blB, 3);
        PREF(bhB, blB, 5); STEP(bhA, blA, 4);
        PREF(bhA, blA, 6); STEP(bhB, blB, 5);
        PREF(bhB, blB, 7); STEP(bhA, blA, 6);
        STEP(bhB, blB, 7);
        if (fg < 2) {
            #pragma unroll
            for (int t = 0; t < 4; t++) {
                const int j = (wid * 4 + t) * 16 + fr;
                const float b = mb1[j];
                #pragma unroll
                for (int rr = 0; rr < 4; rr++)
                    s_h2[fg * 4 + rr][j] = tanhf(acc[t][rr] + b);
            }
        }
    }
    __syncthreads();

    // ---- ent = h2 @ W2 + b2 ----
    if (tid < EPB * NTRI) {
        int e = tid / NTRI, m = tid % NTRI;
        float acc = mb2[m];
        const float* wrow = &W2t[m * H];
        for (int j = 0; j < H; j += 4) {
            const float2 h0 = *(const float2*)&s_h2[e][j];
            const float2 h1 = *(const float2*)&s_h2[e][j + 2];
            const float4 wv = *(const float4*)&wrow[j];
            acc += h0.x * wv.x + h0.y * wv.y + h1.x * wv.z + h1.y * wv.w;
        }
        s_ent[e][m] = acc;
    }
    __syncthreads();

    // ---- per-element: L (to regs), a = L^T dq, ent_bar seeds ----
    if (tid < EPB) {
        const int e = tid;
        const int ti[10] = {0,1,1,2,2,2,3,3,3,3};
        const int tj[10] = {0,0,1,0,1,2,0,1,2,3};
        #pragma unroll
        for (int r = 0; r < 4; r++)
            #pragma unroll
            for (int c = 0; c < 4; c++) Lreg[r][c] = 0.f;
        float sig[10];
        #pragma unroll
        for (int m = 0; m < 10; m++) {
            float v = s_ent[e][m];
            if (ti[m] == tj[m]) {
                sig[m] = 1.f / (1.f + expf(-v));
                Lreg[ti[m]][tj[m]] = softplusf(v);
            } else {
                sig[m] = 1.f;
                Lreg[ti[m]][tj[m]] = v;
            }
        }
        float dq[4];
        #pragma unroll
        for (int r = 0; r < 4; r++) dq[r] = s_qd[e][6 + r];
        float a[4];
        #pragma unroll
        for (int c = 0; c < 4; c++) {
            float s = 0.f;
            #pragma unroll
            for (int r = 0; r < 4; r++) s += Lreg[r][c] * dq[r];
            a[c] = s;
        }
        #pragma unroll
        for (int s = 0; s < 4; s++) {
            #pragma unroll
            for (int m = 0; m < 10; m++) {
                float v = ((ti[m] == s) ? a[tj[m]] : 0.f) + dq[ti[m]] * Lreg[s][tj[m]];
                s_entbar[e][s][m] = v * sig[m];
            }
        }
    }
    __syncthreads();

    // ---- Eh2 seeds -> LDS as pre-split fp16 hi/lo (XOR-swizzled) ----
    {
        const int j = tid;
        float w2row[NTRI];
        #pragma unroll
        for (int m = 0; m < NTRI; m++) w2row[m] = mW2[j * NTRI + m];
        #pragma unroll
        for (int e = 0; e < EPB; e++) {
            const float h = s_h2[e][j];
            const float t2 = 1.f - h * h;
            #pragma unroll
            for (int s = 0; s < 4; s++) {
                float acc = 0.f;
                #pragma unroll
                for (int m = 0; m < NTRI; m++) acc += w2row[m] * s_entbar[e][s][m];
                const float v = acc * t2;
                const int row = e * 4 + s;
                const int idx = row * 256 + (j ^ ((row & 7) << 3));
                _Float16 hi = (_Float16)v;
                s_sH[idx] = hi;
                s_sL[idx] = (_Float16)(v - (float)hi);
            }
        }
    }
    __syncthreads();

    // ---- Eh1 via MFMA (A: pre-split LDS seeds; B: pre-split mW1) + fused J ----
    {
        floatx4 acc[4][2];
        #pragma unroll
        for (int t = 0; t < 4; t++)
            #pragma unroll
            for (int mt = 0; mt < 2; mt++) acc[t][mt] = (floatx4)(0.f);
        half8 bhA[4], blA[4], bhB[4], blB[4];
        auto PREF = [&](half8 (&bh)[4], half8 (&bl)[4], int kc) {
            #pragma unroll
            for (int t = 0; t < 4; t++) {
                const int off = ((wid * 4 + t) * 16 + fr) * H + kc * 32 + kb;
                bh[t] = *(const half8*)&W1m_hi[off];
                bl[t] = *(const half8*)&W1m_lo[off];
            }
        };
        const int swz = (fr & 7) << 3;
        auto STEP = [&](half8 (&bh)[4], half8 (&bl)[4], int kc) {
            half8 ah[2], al[2];
            #pragma unroll
            for (int mt = 0; mt < 2; mt++) {
                const int idx = (mt * 16 + fr) * 256 + ((kc * 32 + kb) ^ swz);
                ah[mt] = *(const half8*)&s_sH[idx];
                al[mt] = *(const half8*)&s_sL[idx];
            }
            #pragma unroll
            for (int t = 0; t < 4; t++) {
                #pragma unroll
                for (int mt = 0; mt < 2; mt++) {
                    acc[t][mt] = MFMA(ah[mt], bh[t], acc[t][mt]);
                    acc[t][mt] = MFMA(ah[mt], bl[t], acc[t][mt]);
                    acc[t][mt] = MFMA(al[mt], bh[t], acc[t][mt]);
                }
            }
        };
        PREF(bhA, blA, 0);
        PREF(bhB, blB, 1); STEP(bhA, blA, 0);
        PREF(bhA, blA, 2); STEP(bhB, blB, 1);
        PREF(bhB, blB, 3); STEP(bhA, blA, 2);
        PREF(bhA, blA, 4); STEP(bhB, blB, 3);
        PREF(bhB, blB, 5); STEP(bhA, blA, 4);
        PREF(bhA, blA, 6); STEP(bhB, blB, 5);
        PREF(bhB, blB, 7); STEP(bhA, blA, 6);
        STEP(bhB, blB, 7);

        // fused J: J[e][s][i] = sum_k W0[i,k] * t1[e][k] * Eh1acc
        float w0v[4][6];
        #pragma unroll
        for (int t = 0; t < 4; t++) {
            const int outk = (wid * 4 + t) * 16 + fr;
            #pragma unroll
            for (int i = 0; i < 6; i++) w0v[t][i] = mW0[i * H + outk];
        }
        #pragma unroll
        for (int mt = 0; mt < 2; mt++) {
            const int e = mt * 4 + fg;
            float part[4][6];
            #pragma unroll
            for (int rr = 0; rr < 4; rr++)
                #pragma unroll
                for (int i = 0; i < 6; i++) part[rr][i] = 0.f;
            #pragma unroll
            for (int t = 0; t < 4; t++) {
                const int outk = (wid * 4 + t) * 16 + fr;
                const float h = s_h1[e][outk];
                const float t1 = 1.f - h * h;
                #pragma unroll
                for (int rr = 0; rr < 4; rr++) {
                    const float v = acc[t][mt][rr] * t1;
                    #pragma unroll
                    for (int i = 0; i < 6; i++) part[rr][i] = fmaf(v, w0v[t][i], part[rr][i]);
                }
            }
            #pragma unroll
            for (int m = 1; m < 16; m <<= 1)
                #pragma unroll
                for (int rr = 0; rr < 4; rr++)
                    #pragma unroll
                    for (int i = 0; i < 6; i++)
                        part[rr][i] += __shfl_xor(part[rr][i], m);
            if (fr == 0) {
                #pragma unroll
                for (int rr = 0; rr < 4; rr++)
                    #pragma unroll
                    for (int i = 0; i < 6; i++)
                        s_Jp[wid][e][rr][i] = part[rr][i];
            }
        }
    }
    __syncthreads();

    // ---- V MLP layer 0 (overwrite s_h1) ----
    {
        const int j = tid;
        float w[QDIM];
        #pragma unroll
        for (int i = 0; i < QDIM; i++) w[i] = vW0[i * H + j];
        const float b = vb0[j];
        #pragma unroll
        for (int e = 0; e < EPB; e++) {
            float z = b;
            #pragma unroll
            for (int i = 0; i < QDIM; i++) z += s_qd[e][i] * w[i];
            s_h1[e][j] = tanhf(z);
        }
    }
    __syncthreads();

    // ---- V layer 1 via MFMA: gg2 = (1-g2^2)*vW2[j] -> s_h2 ----
    {
        floatx4 acc[4];
        #pragma unroll
        for (int t = 0; t < 4; t++) acc[t] = (floatx4)(0.f);
        half8 bhA[4], blA[4], bhB[4], blB[4];
        auto PREF = [&](half8 (&bh)[4], half8 (&bl)[4], int kc) {
            #pragma unroll
            for (int t = 0; t < 4; t++) {
                const int off = ((wid * 4 + t) * 16 + fr) * H + kc * 32 + kb;
                bh[t] = *(const half8*)&V1t_hi[off];
                bl[t] = *(const half8*)&V1t_lo[off];
            }
        };
        auto STEP = [&](half8 (&bh)[4], half8 (&bl)[4], int kc) {
            half8 ah, al;
            split8(&s_h1[fr & 7][kc * 32 + kb], ah, al);
            #pragma unroll
            for (int t = 0; t < 4; t++) {
                acc[t] = MFMA(ah, bh[t], acc[t]);
                acc[t] = MFMA(ah, bl[t], acc[t]);
                acc[t] = MFMA(al, bh[t], acc[t]);
            }
        };
        PREF(bhA, blA, 0);
        PREF(bhB, blB, 1); STEP(bhA, blA, 0);
        PREF(bhA, blA, 2); STEP(bhB, blB, 1);
        PREF(bhB, blB, 3); STEP(bhA, blA, 2);
        PREF(bhA, blA, 4); STEP(bhB, blB, 3);
        PREF(bhB, blB, 5); STEP(bhA, blA, 4);
        PREF(bhA, blA, 6); STEP(bhB, blB, 5);
        PREF(bhB, blB, 7); STEP(bhA, blA, 6);
        STEP(bhB, blB, 7);
        if (fg < 2) {
            #pragma unroll
            for (int t = 0; t < 4; t++) {
                const int j = (wid * 4 + t) * 16 + fr;
                const float b = vb1[j];
                const float w2 = vW2[j];
                #pragma unroll
                for (int rr = 0; rr < 4; rr++) {
                    const float g2 = tanhf(acc[t][rr] + b);
                    s_h2[fg * 4 + rr][j] = (1.f - g2 * g2) * w2;
                }
            }
        }
    }
    __syncthreads();

    // ---- gg1 via MFMA + fused dV ----
    {
        floatx4 acc[4];
        #pragma unroll
        for (int t = 0; t < 4; t++) acc[t] = (floatx4)(0.f);
        half8 bhA[4], blA[4], bhB[4], blB[4];
        auto PREF = [&](half8 (&bh)[4], half8 (&bl)[4], int kc) {
            #pragma unroll
            for (int t = 0; t < 4; t++) {
                const int off = ((wid * 4 + t) * 16 + fr) * H + kc * 32 + kb;
                bh[t] = *(const half8*)&V1m_hi[off];
                bl[t] = *(const half8*)&V1m_lo[off];
            }
        };
        auto STEP = [&](half8 (&bh)[4], half8 (&bl)[4], int kc) {
            half8 ah, al;
            split8(&s_h2[fr & 7][kc * 32 + kb], ah, al);
            #pragma unroll
            for (int t = 0; t < 4; t++) {
                acc[t] = MFMA(ah, bh[t], acc[t]);
                acc[t] = MFMA(ah, bl[t], acc[t]);
                acc[t] = MFMA(al, bh[t], acc[t]);
            }
        };
        PREF(bhA, blA, 0);
        PREF(bhB, blB, 1); STEP(bhA, blA, 0);
        PREF(bhA, blA, 2); STEP(bhB, blB, 1);
        PREF(bhB, blB, 3); STEP(bhA, blA, 2);
        PREF(bhA, blA, 4); STEP(bhB, blB, 3);
        PREF(bhB, blB, 5); STEP(bhA, blA, 4);
        PREF(bhA, blA, 6); STEP(bhB, blB, 5);
        PREF(bhB, blB, 7); STEP(bhA, blA, 6);
        STEP(bhB, blB, 7);

        float w0v[4][6];
        #pragma unroll
        for (int t = 0; t < 4; t++) {
            const int outk = (wid * 4 + t) * 16 + fr;
            #pragma unroll
            for (int i = 0; i < 6; i++) w0v[t][i] = vW0[i * H + outk];
        }
        float part[4][6];
        #pragma unroll
        for (int rr = 0; rr < 4; rr++)
            #pragma unroll
            for (int i = 0; i < 6; i++) part[rr][i] = 0.f;
        #pragma unroll
        for (int t = 0; t < 4; t++) {
            const int outk = (wid * 4 + t) * 16 + fr;
            #pragma unroll
            for (int rr = 0; rr < 4; rr++) {
                const float g = s_h1[(fg * 4 + rr) & 7][outk];
                const float t1 = 1.f - g * g;
                const float v = acc[t][rr] * t1;
                #pragma unroll
                for (int i = 0; i < 6; i++) part[rr][i] = fmaf(v, w0v[t][i], part[rr][i]);
            }
        }
        #pragma unroll
        for (int m = 1; m < 16; m <<= 1)
            #pragma unroll
            for (int rr = 0; rr < 4; rr++)
                #pragma unroll
                for (int i = 0; i < 6; i++)
                    part[rr][i] += __shfl_xor(part[rr][i], m);
        if (fr == 0 && fg < 2) {
            #pragma unroll
            for (int rr = 0; rr < 4; rr++)
                #pragma unroll
                for (int i = 0; i < 6; i++)
                    s_dVp[wid][fg * 4 + rr][i] = part[rr][i];
        }
    }
    __syncthreads();

    // ---- finalize per element ----
    if (tid < EPB && (e0 + tid) < n) {
        const int e = tid;
        float q[6], dq[4];
        #pragma unroll
        for (int i = 0; i < 6; i++) q[i] = s_qd[e][i];
        #pragma unroll
        for (int r = 0; r < 4; r++) dq[r] = s_qd[e][6 + r];
        const float x1a = q[2], x1b = q[3], x2a = q[4], x2b = q[5];
        float J[4][6];
        #pragma unroll
        for (int r = 0; r < 4; r++)
            #pragma unroll
            for (int i = 0; i < 6; i++)
                J[r][i] = s_Jp[0][e][r][i] + s_Jp[1][e][r][i] + s_Jp[2][e][r][i] + s_Jp[3][e][r][i];
        float dV[6];
        #pragma unroll
        for (int i = 0; i < 6; i++)
            dV[i] = s_dVp[0][e][i] + s_dVp[1][e][i] + s_dVp[2][e][i] + s_dVp[3][e][i];

        float G[4][4];
        #pragma unroll
        for (int r = 0; r < 4; r++) {
            G[r][0] = J[r][0];
            G[r][1] = J[r][1];
            G[r][2] = -x2a * J[r][2] + x1a * J[r][4];
            G[r][3] = -x2b * J[r][3] + x1b * J[r][5];
        }
        float gL[6];
        #pragma unroll
        for (int i = 0; i < 6; i++) {
            float s = 0.f;
            #pragma unroll
            for (int r = 0; r < 4; r++) s += dq[r] * J[r][i];
            gL[i] = 0.5f * s - dV[i];
        }
        float dLdq[4];
        dLdq[0] = gL[0];
        dLdq[1] = gL[1];
        dLdq[2] = -x2a * gL[2] + x1a * gL[4];
        dLdq[3] = -x2b * gL[3] + x1b * gL[5];
        float b[4];
        #pragma unroll
        for (int r = 0; r < 4; r++) {
            float s = 0.f;
            #pragma unroll
            for (int c = 0; c < 4; c++) s += G[r][c] * dq[c];
            b[r] = dLdq[r] - s;
        }
        float M[4][4];
        #pragma unroll
        for (int r = 0; r < 4; r++)
            #pragma unroll
            for (int c = 0; c <= r; c++) {
                float s = 0.f;
                #pragma unroll
                for (int k = 0; k < 4; k++) s += Lreg[r][k] * Lreg[c][k];
                M[r][c] = s;
            }
        #pragma unroll
        for (int r = 0; r < 4; r++) M[r][r] += EPS;
        float C00 = sqrtf(M[0][0]);
        float C10 = M[1][0] / C00, C20 = M[2][0] / C00, C30 = M[3][0] / C00;
        float C11 = sqrtf(M[1][1] - C10 * C10);
        float C21 = (M[2][1] - C20 * C10) / C11;
        float C31 = (M[3][1] - C30 * C10) / C11;
        float C22 = sqrtf(M[2][2] - C20 * C20 - C21 * C21);
        float C32 = (M[3][2] - C30 * C20 - C31 * C21) / C22;
        float C33 = sqrtf(M[3][3] - C30 * C30 - C31 * C31 - C32 * C32);
        float y0 = b[0] / C00;
        float y1 = (b[1] - C10 * y0) / C11;
        float y2 = (b[2] - C20 * y0 - C21 * y1) / C22;
        float y3 = (b[3] - C30 * y0 - C31 * y1 - C32 * y2) / C33;
        float d3 = y3 / C33;
        float d2 = (y2 - C32 * d3) / C22;
        float d1 = (y1 - C21 * d2 - C31 * d3) / C11;
        float d0 = (y0 - C10 * d1 - C20 * d2 - C30 * d3) / C00;

        float* o = &out[(e0 + e) * 10];
        o[0] = dq[0];
        o[1] = dq[1];
        o[2] = -x2a * dq[2];
        o[3] = -x2b * dq[3];
        o[4] = x1a * dq[2];
        o[5] = x1b * dq[3];
        o[6] = d0; o[7] = d1; o[8] = d2; o[9] = d3;
    }
}

extern "C" void kernel_launch(void* const* d_in, const int* in_sizes, int n_in,
                              void* d_out, int out_size, void* d_ws, size_t ws_size,
                              hipStream_t stream) {
    const float* x   = (const float*)d_in[0];
    const float* mW0 = (const float*)d_in[1];
    const float* mb0 = (const float*)d_in[2];
    const float* mW1 = (const float*)d_in[3];
    const float* mb1 = (const float*)d_in[4];
    const float* mW2 = (const float*)d_in[5];
    const float* mb2 = (const float*)d_in[6];
    const float* vW0 = (const float*)d_in[7];
    const float* vb0 = (const float*)d_in[8];
    const float* vW1 = (const float*)d_in[9];
    const float* vb1 = (const float*)d_in[10];
    const float* vW2 = (const float*)d_in[11];
    float* out = (float*)d_out;
    const int n = in_sizes[0] / 10;

    prep_kernel<<<H, H, 0, stream>>>(mW1, vW1, mW2, d_ws);

    const int blocks = (n + EPB - 1) / EPB;
    lnn_kernel<<<blocks, 256, 0, stream>>>(x, mW0, mb0, mb1, mW2, mb2,
                                           vW0, vb0, vb1, vW2,
                                           d_ws, out, n);
}

// Round 9
// 808.749 us; speedup vs baseline: 1.5953x; 1.3595x over previous
//
#include <hip/hip_runtime.h>
#include <math.h>

#define EPS 1e-3f
#define H 256
#define QDIM 6
#define NTRI 10
#define EPB 16
#define PADH 260   // fp32 row pad: 1040B rows, 16B-aligned, 2-way-free banks

typedef _Float16 half8 __attribute__((ext_vector_type(8)));
typedef float floatx4 __attribute__((ext_vector_type(4)));

#define WSZ (H * H)

__device__ __forceinline__ float softplusf(float x) {
    if (x > 20.f) return x;
    return log1pf(expf(x));
}

__device__ __forceinline__ void split8(const float* __restrict__ p, half8& hi, half8& lo) {
    #pragma unroll
    for (int i = 0; i < 8; i++) {
        float a = p[i];
        _Float16 h = (_Float16)a;
        hi[i] = h;
        lo[i] = (_Float16)(a - (float)h);
    }
}

#define MFMA(A, B, C) __builtin_amdgcn_mfma_f32_16x16x32_f16((A), (B), (C), 0, 0, 0)

// ---- prep: pre-split weights to fp16 hi/lo in both layouts; transpose mW2 ----
__global__ __launch_bounds__(256) void prep_kernel(
    const float* __restrict__ mW1, const float* __restrict__ vW1,
    const float* __restrict__ mW2, void* __restrict__ ws)
{
    _Float16* h = (_Float16*)ws;
    float* W2t = (float*)(h + 8 * WSZ);
    const int k = blockIdx.x;
    const int j = threadIdx.x;
    {
        float a = mW1[k * H + j];
        _Float16 hi = (_Float16)a;
        _Float16 lo = (_Float16)(a - (float)hi);
        h[0 * WSZ + j * H + k] = hi;   // W1t_hi
        h[1 * WSZ + j * H + k] = lo;   // W1t_lo
        h[2 * WSZ + k * H + j] = hi;   // W1m_hi
        h[3 * WSZ + k * H + j] = lo;   // W1m_lo
    }
    {
        float a = vW1[k * H + j];
        _Float16 hi = (_Float16)a;
        _Float16 lo = (_Float16)(a - (float)hi);
        h[4 * WSZ + j * H + k] = hi;   // V1t_hi
        h[5 * WSZ + j * H + k] = lo;   // V1t_lo
        h[6 * WSZ + k * H + j] = hi;   // V1m_hi
        h[7 * WSZ + k * H + j] = lo;   // V1m_lo
    }
    if (k < NTRI) W2t[k * H + j] = mW2[j * NTRI + k];
}

__global__ __launch_bounds__(256, 2) void lnn_kernel(
    const float* __restrict__ x,
    const float* __restrict__ mW0, const float* __restrict__ mb0,
    const float* __restrict__ mb1,
    const float* __restrict__ mW2, const float* __restrict__ mb2,
    const float* __restrict__ vW0, const float* __restrict__ vb0,
    const float* __restrict__ vb1,
    const float* __restrict__ vW2,
    const void* __restrict__ ws,
    float* __restrict__ out, int n)
{
    const _Float16* wsh = (const _Float16*)ws;
    const _Float16* W1t_hi = wsh + 0 * WSZ;
    const _Float16* W1t_lo = wsh + 1 * WSZ;
    const _Float16* W1m_hi = wsh + 2 * WSZ;
    const _Float16* W1m_lo = wsh + 3 * WSZ;
    const _Float16* V1t_hi = wsh + 4 * WSZ;
    const _Float16* V1t_lo = wsh + 5 * WSZ;
    const _Float16* V1m_hi = wsh + 6 * WSZ;
    const _Float16* V1m_lo = wsh + 7 * WSZ;
    const float*    W2t    = (const float*)(wsh + 8 * WSZ);

    __shared__ float s_qd[EPB][10];
    __shared__ float s_h1[EPB][PADH];        // g1, then h1
    __shared__ float s_h2[EPB][PADH];        // gg2, then h2
    __shared__ float s_sd[32][PADH];         // Eh1 seeds (one 8-element stage)
    __shared__ float s_ent[EPB][NTRI];
    __shared__ float s_entbar[EPB][4][NTRI];
    __shared__ float s_Jp[4][EPB][4][6];     // [wid][e][s][i]
    __shared__ float s_dVp[4][EPB][6];       // [wid][e][i]

    const int tid = threadIdx.x;
    const int e0 = blockIdx.x * EPB;
    const int lane = tid & 63;
    const int wid = tid >> 6;
    const int fr = lane & 15;
    const int fg = lane >> 4;
    const int kb = fg * 8;

    float Lreg[4][4];   // threads 0..15 (entbar producer == finalize consumer)

    // ---- load q, dq ----
    if (tid < EPB * 10) {
        int e = tid / 10, c = tid % 10;
        int ge = e0 + e;
        s_qd[e][c] = (ge < n) ? x[ge * 10 + c] : 0.f;
    }
    __syncthreads();

    // ================= V chain =================
    // ---- V layer 0: g1 ----
    {
        const int j = tid;
        float w[QDIM];
        #pragma unroll
        for (int i = 0; i < QDIM; i++) w[i] = vW0[i * H + j];
        const float b = vb0[j];
        #pragma unroll
        for (int e = 0; e < EPB; e++) {
            float z = b;
            #pragma unroll
            for (int i = 0; i < QDIM; i++) z += s_qd[e][i] * w[i];
            s_h1[e][j] = tanhf(z);
        }
    }
    __syncthreads();

    // ---- V layer 1 MFMA: gg2 = (1-g2^2)*vW2[j] -> s_h2 ----
    {
        floatx4 acc[4];
        #pragma unroll
        for (int t = 0; t < 4; t++) acc[t] = (floatx4)(0.f);
        half8 bhA[4], blA[4], bhB[4], blB[4];
        auto PREF = [&](half8 (&bh)[4], half8 (&bl)[4], int kc) {
            #pragma unroll
            for (int t = 0; t < 4; t++) {
                const int off = ((wid * 4 + t) * 16 + fr) * H + kc * 32 + kb;
                bh[t] = *(const half8*)&V1t_hi[off];
                bl[t] = *(const half8*)&V1t_lo[off];
            }
        };
        auto STEP = [&](half8 (&bh)[4], half8 (&bl)[4], int kc) {
            half8 ah, al;
            split8(&s_h1[fr][kc * 32 + kb], ah, al);
            #pragma unroll
            for (int t = 0; t < 4; t++) {
                acc[t] = MFMA(ah, bh[t], acc[t]);
                acc[t] = MFMA(ah, bl[t], acc[t]);
                acc[t] = MFMA(al, bh[t], acc[t]);
            }
        };
        PREF(bhA, blA, 0);
        PREF(bhB, blB, 1); STEP(bhA, blA, 0);
        PREF(bhA, blA, 2); STEP(bhB, blB, 1);
        PREF(bhB, blB, 3); STEP(bhA, blA, 2);
        PREF(bhA, blA, 4); STEP(bhB, blB, 3);
        PREF(bhB, blB, 5); STEP(bhA, blA, 4);
        PREF(bhA, blA, 6); STEP(bhB, blB, 5);
        PREF(bhB, blB, 7); STEP(bhA, blA, 6);
        STEP(bhB, blB, 7);
        #pragma unroll
        for (int t = 0; t < 4; t++) {
            const int j = (wid * 4 + t) * 16 + fr;
            const float b = vb1[j];
            const float w2 = vW2[j];
            #pragma unroll
            for (int rr = 0; rr < 4; rr++) {
                const int e = fg * 4 + rr;
                const float g2 = tanhf(acc[t][rr] + b);
                s_h2[e][j] = (1.f - g2 * g2) * w2;
            }
        }
    }
    __syncthreads();

    // ---- gg1 MFMA + fused dV ----
    {
        floatx4 acc[4];
        #pragma unroll
        for (int t = 0; t < 4; t++) acc[t] = (floatx4)(0.f);
        half8 bhA[4], blA[4], bhB[4], blB[4];
        auto PREF = [&](half8 (&bh)[4], half8 (&bl)[4], int kc) {
            #pragma unroll
            for (int t = 0; t < 4; t++) {
                const int off = ((wid * 4 + t) * 16 + fr) * H + kc * 32 + kb;
                bh[t] = *(const half8*)&V1m_hi[off];
                bl[t] = *(const half8*)&V1m_lo[off];
            }
        };
        auto STEP = [&](half8 (&bh)[4], half8 (&bl)[4], int kc) {
            half8 ah, al;
            split8(&s_h2[fr][kc * 32 + kb], ah, al);
            #pragma unroll
            for (int t = 0; t < 4; t++) {
                acc[t] = MFMA(ah, bh[t], acc[t]);
                acc[t] = MFMA(ah, bl[t], acc[t]);
                acc[t] = MFMA(al, bh[t], acc[t]);
            }
        };
        PREF(bhA, blA, 0);
        PREF(bhB, blB, 1); STEP(bhA, blA, 0);
        PREF(bhA, blA, 2); STEP(bhB, blB, 1);
        PREF(bhB, blB, 3); STEP(bhA, blA, 2);
        PREF(bhA, blA, 4); STEP(bhB, blB, 3);
        PREF(bhB, blB, 5); STEP(bhA, blA, 4);
        PREF(bhA, blA, 6); STEP(bhB, blB, 5);
        PREF(bhB, blB, 7); STEP(bhA, blA, 6);
        STEP(bhB, blB, 7);

        float w0v[4][6];
        #pragma unroll
        for (int t = 0; t < 4; t++) {
            const int outk = (wid * 4 + t) * 16 + fr;
            #pragma unroll
            for (int i = 0; i < 6; i++) w0v[t][i] = vW0[i * H + outk];
        }
        float part[4][6];
        #pragma unroll
        for (int rr = 0; rr < 4; rr++)
            #pragma unroll
            for (int i = 0; i < 6; i++) part[rr][i] = 0.f;
        #pragma unroll
        for (int t = 0; t < 4; t++) {
            const int outk = (wid * 4 + t) * 16 + fr;
            #pragma unroll
            for (int rr = 0; rr < 4; rr++) {
                const float g = s_h1[fg * 4 + rr][outk];
                const float t1 = 1.f - g * g;
                const float v = acc[t][rr] * t1;
                #pragma unroll
                for (int i = 0; i < 6; i++) part[rr][i] = fmaf(v, w0v[t][i], part[rr][i]);
            }
        }
        #pragma unroll
        for (int m = 1; m < 16; m <<= 1)
            #pragma unroll
            for (int rr = 0; rr < 4; rr++)
                #pragma unroll
                for (int i = 0; i < 6; i++)
                    part[rr][i] += __shfl_xor(part[rr][i], m);
        if (fr == 0) {
            #pragma unroll
            for (int rr = 0; rr < 4; rr++)
                #pragma unroll
                for (int i = 0; i < 6; i++)
                    s_dVp[wid][fg * 4 + rr][i] = part[rr][i];
        }
    }
    __syncthreads();

    // ================= mass chain =================
    // ---- mass layer 0: h1 (overwrite g1) ----
    {
        const int j = tid;
        float w[QDIM];
        #pragma unroll
        for (int i = 0; i < QDIM; i++) w[i] = mW0[i * H + j];
        const float b = mb0[j];
        #pragma unroll
        for (int e = 0; e < EPB; e++) {
            float z = b;
            #pragma unroll
            for (int i = 0; i < QDIM; i++) z += s_qd[e][i] * w[i];
            s_h1[e][j] = tanhf(z);
        }
    }
    __syncthreads();

    // ---- mass layer 1 MFMA: h2 = tanh(h1 @ W1 + b1) -> s_h2 ----
    {
        floatx4 acc[4];
        #pragma unroll
        for (int t = 0; t < 4; t++) acc[t] = (floatx4)(0.f);
        half8 bhA[4], blA[4], bhB[4], blB[4];
        auto PREF = [&](half8 (&bh)[4], half8 (&bl)[4], int kc) {
            #pragma unroll
            for (int t = 0; t < 4; t++) {
                const int off = ((wid * 4 + t) * 16 + fr) * H + kc * 32 + kb;
                bh[t] = *(const half8*)&W1t_hi[off];
                bl[t] = *(const half8*)&W1t_lo[off];
            }
        };
        auto STEP = [&](half8 (&bh)[4], half8 (&bl)[4], int kc) {
            half8 ah, al;
            split8(&s_h1[fr][kc * 32 + kb], ah, al);
            #pragma unroll
            for (int t = 0; t < 4; t++) {
                acc[t] = MFMA(ah, bh[t], acc[t]);
                acc[t] = MFMA(ah, bl[t], acc[t]);
                acc[t] = MFMA(al, bh[t], acc[t]);
            }
        };
        PREF(bhA, blA, 0);
        PREF(bhB, blB, 1); STEP(bhA, blA, 0);
        PREF(bhA, blA, 2); STEP(bhB, blB, 1);
        PREF(bhB, blB, 3); STEP(bhA, blA, 2);
        PREF(bhA, blA, 4); STEP(bhB, blB, 3);
        PREF(bhB, blB, 5); STEP(bhA, blA, 4);
        PREF(bhA, blA, 6); STEP(bhB, blB, 5);
        PREF(bhB, blB, 7); STEP(bhA, blA, 6);
        STEP(bhB, blB, 7);
        #pragma unroll
        for (int t = 0; t < 4; t++) {
            const int j = (wid * 4 + t) * 16 + fr;
            const float b = mb1[j];
            #pragma unroll
            for (int rr = 0; rr < 4; rr++)
                s_h2[fg * 4 + rr][j] = tanhf(acc[t][rr] + b);
        }
    }
    __syncthreads();

    // ---- ent = h2 @ W2 + b2 ----
    if (tid < EPB * NTRI) {
        int e = tid / NTRI, m = tid % NTRI;
        float acc = mb2[m];
        const float* wrow = &W2t[m * H];
        for (int j = 0; j < H; j += 4) {
            const float2 h0 = *(const float2*)&s_h2[e][j];
            const float2 h1 = *(const float2*)&s_h2[e][j + 2];
            const float4 wv = *(const float4*)&wrow[j];
            acc += h0.x * wv.x + h0.y * wv.y + h1.x * wv.z + h1.y * wv.w;
        }
        s_ent[e][m] = acc;
    }
    __syncthreads();

    // ---- per-element: L (regs), a = L^T dq, ent_bar seeds ----
    if (tid < EPB) {
        const int e = tid;
        const int ti[10] = {0,1,1,2,2,2,3,3,3,3};
        const int tj[10] = {0,0,1,0,1,2,0,1,2,3};
        #pragma unroll
        for (int r = 0; r < 4; r++)
            #pragma unroll
            for (int c = 0; c < 4; c++) Lreg[r][c] = 0.f;
        float sig[10];
        #pragma unroll
        for (int m = 0; m < 10; m++) {
            float v = s_ent[e][m];
            if (ti[m] == tj[m]) {
                sig[m] = 1.f / (1.f + expf(-v));
                Lreg[ti[m]][tj[m]] = softplusf(v);
            } else {
                sig[m] = 1.f;
                Lreg[ti[m]][tj[m]] = v;
            }
        }
        float dq[4];
        #pragma unroll
        for (int r = 0; r < 4; r++) dq[r] = s_qd[e][6 + r];
        float a[4];
        #pragma unroll
        for (int c = 0; c < 4; c++) {
            float s = 0.f;
            #pragma unroll
            for (int r = 0; r < 4; r++) s += Lreg[r][c] * dq[r];
            a[c] = s;
        }
        #pragma unroll
        for (int s = 0; s < 4; s++) {
            #pragma unroll
            for (int m = 0; m < 10; m++) {
                float v = ((ti[m] == s) ? a[tj[m]] : 0.f) + dq[ti[m]] * Lreg[s][tj[m]];
                s_entbar[e][s][m] = v * sig[m];
            }
        }
    }
    __syncthreads();

    // ---- Eh1 in 2 stages of 8 elements ----
    for (int hstage = 0; hstage < 2; hstage++) {
        // seeds: rows el*4+s for e = hstage*8+el
        {
            const int j = tid;
            float w2row[NTRI];
            #pragma unroll
            for (int m = 0; m < NTRI; m++) w2row[m] = mW2[j * NTRI + m];
            #pragma unroll
            for (int el = 0; el < 8; el++) {
                const int e = hstage * 8 + el;
                const float h = s_h2[e][j];
                const float t2 = 1.f - h * h;
                #pragma unroll
                for (int s = 0; s < 4; s++) {
                    float acc = 0.f;
                    #pragma unroll
                    for (int m = 0; m < NTRI; m++) acc += w2row[m] * s_entbar[e][s][m];
                    s_sd[el * 4 + s][j] = acc * t2;
                }
            }
        }
        __syncthreads();

        // Eh1 MFMA + fused J
        {
            floatx4 acc[4][2];
            #pragma unroll
            for (int t = 0; t < 4; t++)
                #pragma unroll
                for (int mt = 0; mt < 2; mt++) acc[t][mt] = (floatx4)(0.f);
            half8 bhA[4], blA[4], bhB[4], blB[4];
            auto PREF = [&](half8 (&bh)[4], half8 (&bl)[4], int kc) {
                #pragma unroll
                for (int t = 0; t < 4; t++) {
                    const int off = ((wid * 4 + t) * 16 + fr) * H + kc * 32 + kb;
                    bh[t] = *(const half8*)&W1m_hi[off];
                    bl[t] = *(const half8*)&W1m_lo[off];
                }
            };
            auto STEP = [&](half8 (&bh)[4], half8 (&bl)[4], int kc) {
                half8 ah[2], al[2];
                #pragma unroll
                for (int mt = 0; mt < 2; mt++)
                    split8(&s_sd[mt * 16 + fr][kc * 32 + kb], ah[mt], al[mt]);
                #pragma unroll
                for (int t = 0; t < 4; t++) {
                    #pragma unroll
                    for (int mt = 0; mt < 2; mt++) {
                        acc[t][mt] = MFMA(ah[mt], bh[t], acc[t][mt]);
                        acc[t][mt] = MFMA(ah[mt], bl[t], acc[t][mt]);
                        acc[t][mt] = MFMA(al[mt], bh[t], acc[t][mt]);
                    }
                }
            };
            PREF(bhA, blA, 0);
            PREF(bhB, blB, 1); STEP(bhA, blA, 0);
            PREF(bhA, blA, 2); STEP(bhB, blB, 1);
            PREF(bhB, blB, 3); STEP(bhA, blA, 2);
            PREF(bhA, blA, 4); STEP(bhB, blB, 3);
            PREF(bhB, blB, 5); STEP(bhA, blA, 4);
            PREF(bhA, blA, 6); STEP(bhB, blB, 5);
            PREF(bhB, blB, 7); STEP(bhA, blA, 6);
            STEP(bhB, blB, 7);

            float w0v[4][6];
            #pragma unroll
            for (int t = 0; t < 4; t++) {
                const int outk = (wid * 4 + t) * 16 + fr;
                #pragma unroll
                for (int i = 0; i < 6; i++) w0v[t][i] = mW0[i * H + outk];
            }
            #pragma unroll
            for (int mt = 0; mt < 2; mt++) {
                const int e = hstage * 8 + mt * 4 + fg;
                float part[4][6];
                #pragma unroll
                for (int rr = 0; rr < 4; rr++)
                    #pragma unroll
                    for (int i = 0; i < 6; i++) part[rr][i] = 0.f;
                #pragma unroll
                for (int t = 0; t < 4; t++) {
                    const int outk = (wid * 4 + t) * 16 + fr;
                    const float h = s_h1[e][outk];
                    const float t1 = 1.f - h * h;
                    #pragma unroll
                    for (int rr = 0; rr < 4; rr++) {
                        const float v = acc[t][mt][rr] * t1;
                        #pragma unroll
                        for (int i = 0; i < 6; i++) part[rr][i] = fmaf(v, w0v[t][i], part[rr][i]);
                    }
                }
                #pragma unroll
                for (int m = 1; m < 16; m <<= 1)
                    #pragma unroll
                    for (int rr = 0; rr < 4; rr++)
                        #pragma unroll
                        for (int i = 0; i < 6; i++)
                            part[rr][i] += __shfl_xor(part[rr][i], m);
                if (fr == 0) {
                    #pragma unroll
                    for (int rr = 0; rr < 4; rr++)
                        #pragma unroll
                        for (int i = 0; i < 6; i++)
                            s_Jp[wid][e][rr][i] = part[rr][i];
                }
            }
        }
        __syncthreads();
    }

    // ---- finalize per element ----
    if (tid < EPB && (e0 + tid) < n) {
        const int e = tid;
        float q[6], dq[4];
        #pragma unroll
        for (int i = 0; i < 6; i++) q[i] = s_qd[e][i];
        #pragma unroll
        for (int r = 0; r < 4; r++) dq[r] = s_qd[e][6 + r];
        const float x1a = q[2], x1b = q[3], x2a = q[4], x2b = q[5];
        float J[4][6];
        #pragma unroll
        for (int r = 0; r < 4; r++)
            #pragma unroll
            for (int i = 0; i < 6; i++)
                J[r][i] = s_Jp[0][e][r][i] + s_Jp[1][e][r][i] + s_Jp[2][e][r][i] + s_Jp[3][e][r][i];
        float dV[6];
        #pragma unroll
        for (int i = 0; i < 6; i++)
            dV[i] = s_dVp[0][e][i] + s_dVp[1][e][i] + s_dVp[2][e][i] + s_dVp[3][e][i];

        float G[4][4];
        #pragma unroll
        for (int r = 0; r < 4; r++) {
            G[r][0] = J[r][0];
            G[r][1] = J[r][1];
            G[r][2] = -x2a * J[r][2] + x1a * J[r][4];
            G[r][3] = -x2b * J[r][3] + x1b * J[r][5];
        }
        float gL[6];
        #pragma unroll
        for (int i = 0; i < 6; i++) {
            float s = 0.f;
            #pragma unroll
            for (int r = 0; r < 4; r++) s += dq[r] * J[r][i];
            gL[i] = 0.5f * s - dV[i];
        }
        float dLdq[4];
        dLdq[0] = gL[0];
        dLdq[1] = gL[1];
        dLdq[2] = -x2a * gL[2] + x1a * gL[4];
        dLdq[3] = -x2b * gL[3] + x1b * gL[5];
        float b[4];
        #pragma unroll
        for (int r = 0; r < 4; r++) {
            float s = 0.f;
            #pragma unroll
            for (int c = 0; c < 4; c++) s += G[r][c] * dq[c];
            b[r] = dLdq[r] - s;
        }
        float M[4][4];
        #pragma unroll
        for (int r = 0; r < 4; r++)
            #pragma unroll
            for (int c = 0; c <= r; c++) {
                float s = 0.f;
                #pragma unroll
                for (int k = 0; k < 4; k++) s += Lreg[r][k] * Lreg[c][k];
                M[r][c] = s;
            }
        #pragma unroll
        for (int r = 0; r < 4; r++) M[r][r] += EPS;
        float C00 = sqrtf(M[0][0]);
        float C10 = M[1][0] / C00, C20 = M[2][0] / C00, C30 = M[3][0] / C00;
        float C11 = sqrtf(M[1][1] - C10 * C10);
        float C21 = (M[2][1] - C20 * C10) / C11;
        float C31 = (M[3][1] - C30 * C10) / C11;
        float C22 = sqrtf(M[2][2] - C20 * C20 - C21 * C21);
        float C32 = (M[3][2] - C30 * C20 - C31 * C21) / C22;
        float C33 = sqrtf(M[3][3] - C30 * C30 - C31 * C31 - C32 * C32);
        float y0 = b[0] / C00;
        float y1 = (b[1] - C10 * y0) / C11;
        float y2 = (b[2] - C20 * y0 - C21 * y1) / C22;
        float y3 = (b[3] - C30 * y0 - C31 * y1 - C32 * y2) / C33;
        float d3 = y3 / C33;
        float d2 = (y2 - C32 * d3) / C22;
        float d1 = (y1 - C21 * d2 - C31 * d3) / C11;
        float d0 = (y0 - C10 * d1 - C20 * d2 - C30 * d3) / C00;

        float* o = &out[(e0 + e) * 10];
        o[0] = dq[0];
        o[1] = dq[1];
        o[2] = -x2a * dq[2];
        o[3] = -x2b * dq[3];
        o[4] = x1a * dq[2];
        o[5] = x1b * dq[3];
        o[6] = d0; o[7] = d1; o[8] = d2; o[9] = d3;
    }
}

extern "C" void kernel_launch(void* const* d_in, const int* in_sizes, int n_in,
                              void* d_out, int out_size, void* d_ws, size_t ws_size,
                              hipStream_t stream) {
    const float* x   = (const float*)d_in[0];
    const float* mW0 = (const float*)d_in[1];
    const float* mb0 = (const float*)d_in[2];
    const float* mW1 = (const float*)d_in[3];
    const float* mb1 = (const float*)d_in[4];
    const float* mW2 = (const float*)d_in[5];
    const float* mb2 = (const float*)d_in[6];
    const float* vW0 = (const float*)d_in[7];
    const float* vb0 = (const float*)d_in[8];
    const float* vW1 = (const float*)d_in[9];
    const float* vb1 = (const float*)d_in[10];
    const float* vW2 = (const float*)d_in[11];
    float* out = (float*)d_out;
    const int n = in_sizes[0] / 10;

    prep_kernel<<<H, H, 0, stream>>>(mW1, vW1, mW2, d_ws);

    const int blocks = (n + EPB - 1) / EPB;
    lnn_kernel<<<blocks, 256, 0, stream>>>(x, mW0, mb0, mb1, mW2, mb2,
                                           vW0, vb0, vb1, vW2,
                                           d_ws, out, n);
}